// Round 1
// baseline (352.951 us; speedup 1.0000x reference)
//
#include <hip/hip_runtime.h>
#include <hip/hip_bf16.h>

typedef __attribute__((ext_vector_type(8))) short bf16x8;
typedef __attribute__((ext_vector_type(4))) float f32x4;
typedef __attribute__((ext_vector_type(4))) unsigned short u16x4;
typedef __attribute__((ext_vector_type(8))) unsigned short u16x8;

#define B_DIM 8192
#define H_DIM 1024
#define K_DIM 2048
#define N_DIM 4096
#define BH (B_DIM * H_DIM)

__device__ __forceinline__ unsigned short f2bf(float f) {
    union { float f; unsigned u; } v; v.f = f;
    unsigned r = v.u + 0x7FFFu + ((v.u >> 16) & 1u);   // round-to-nearest-even
    return (unsigned short)(r >> 16);
}

__device__ __forceinline__ void gload16(const void* g, void* l) {
    __builtin_amdgcn_global_load_lds(
        (const __attribute__((address_space(1))) void*)g,
        (__attribute__((address_space(3))) void*)l, 16, 0, 0);
}

// ---------------------------------------------------------------------------
// Kernel 1: pack [x | h] (fp32) -> bf16 A[8192][2048] row-major
// ---------------------------------------------------------------------------
__global__ void build_a(const float* __restrict__ x, const float* __restrict__ h,
                        unsigned short* __restrict__ Abf) {
    int gid = blockIdx.x * 256 + threadIdx.x;       // one float4 per thread
    int m   = gid >> 9;                             // / 512  (512 float4 per row)
    int rem = gid & 511;
    int p   = rem >> 8;                             // 0 = x half, 1 = h half
    int k4  = rem & 255;
    const float* src = (p ? h : x) + m * 1024 + k4 * 4;
    float4 v = *(const float4*)src;
    u16x4 o = { f2bf(v.x), f2bf(v.y), f2bf(v.z), f2bf(v.w) };
    *(u16x4*)(Abf + (size_t)gid * 4) = o;
}

// ---------------------------------------------------------------------------
// Kernel 2: W = [Wx; Wh] (fp32 [2048][4096]) -> bf16 Bperm, gate-permuted B^T.
// Row mapping: n = gate*1024 + j; jb=j>>5, jj=j&31 ->
//   R = jb*128 + (jj>>4)*64 + gate*16 + (jj&15),  Bperm[R][k] = W[k][n]
// ---------------------------------------------------------------------------
__global__ void build_b(const float* __restrict__ Wx, const float* __restrict__ Wh,
                        unsigned short* __restrict__ Bperm) {
    __shared__ float tile[64][65];                  // +1 pad: conflict-free col reads
    const int t  = threadIdx.x;
    const int k0 = blockIdx.x * 64;                 // 32 blocks over K
    const int n0 = blockIdx.y * 64;                 // 64 blocks over N
    // load 64x64 fp32 tile, coalesced along n
#pragma unroll
    for (int it = 0; it < 4; ++it) {
        int lin = it * 256 + t;                     // 0..1023 float4 slots
        int kl  = lin >> 4;                         // 0..63
        int n4  = lin & 15;                         // 0..15
        int k   = k0 + kl;
        const float* src = (k < 1024) ? (Wx + (size_t)k * 4096 + n0 + n4 * 4)
                                      : (Wh + (size_t)(k - 1024) * 4096 + n0 + n4 * 4);
        float4 v = *(const float4*)src;
        tile[kl][n4 * 4 + 0] = v.x;
        tile[kl][n4 * 4 + 1] = v.y;
        tile[kl][n4 * 4 + 2] = v.z;
        tile[kl][n4 * 4 + 3] = v.w;
    }
    __syncthreads();
    // write transposed, coalesced along k, 8 bf16 (16B) per store
#pragma unroll
    for (int it = 0; it < 2; ++it) {
        int lin = it * 256 + t;                     // 0..511
        int nl  = lin >> 3;                         // 0..63
        int ch  = lin & 7;                          // 0..7 (k chunk of 8)
        int n    = n0 + nl;
        int gate = n >> 10;
        int j    = n & 1023;
        int jb   = j >> 5;
        int jj   = j & 31;
        int R    = jb * 128 + (jj >> 4) * 64 + gate * 16 + (jj & 15);
        u16x8 o;
#pragma unroll
        for (int q = 0; q < 8; ++q) o[q] = f2bf(tile[ch * 8 + q][nl]);
        *(u16x8*)(Bperm + (size_t)R * 2048 + k0 + ch * 8) = o;
    }
}

// ---------------------------------------------------------------------------
// Kernel 3: fused GEMM + LSTM epilogue.
// 128x128 tile (M x [4 gates x 32 j]), BK=64, 4 waves, 16x16x32 bf16 MFMA.
// Lane holds all 4 gates of one (row, j) across tn=0..3 -> shuffle-free epilogue.
// ---------------------------------------------------------------------------
__global__ __launch_bounds__(256, 2) void lstm_fused(
    const unsigned short* __restrict__ Abf,   // [8192][2048] bf16
    const unsigned short* __restrict__ Bperm, // [4096][2048] bf16 (permuted B^T)
    const float* __restrict__ bx, const float* __restrict__ bh,
    const float* __restrict__ cin, float* __restrict__ out) {
    __shared__ unsigned short lsA[128 * 64];
    __shared__ unsigned short lsB[128 * 64];

    const int tid  = threadIdx.x;
    const int wave = tid >> 6;
    const int lane = tid & 63;
    const int m0 = blockIdx.x * 128;
    const int jb = blockIdx.y;                  // 0..31
    const int wm = wave >> 1;                   // 0..1 row half
    const int wn = wave & 1;                    // 0..1 col half

    f32x4 acc[4][4];
#pragma unroll
    for (int i = 0; i < 4; ++i)
#pragma unroll
        for (int j = 0; j < 4; ++j) acc[i][j] = (f32x4){0.f, 0.f, 0.f, 0.f};

    // staging: 16KB tile = 256 threads x 4 iters x 16B; LDS dest = waveBase + lane*16
    const int sRow   = tid >> 3;                // 0..31 (+ it*32)
    const int sChunk = (tid & 7) * 8;           // bf16 col offset
    const int aBase = (m0 + sRow) * K_DIM + sChunk;
    const int bBase = (jb * 128 + sRow) * K_DIM + sChunk;

    const int fRow = lane & 15;
    const int fK   = (lane >> 4) * 8;

    for (int kt = 0; kt < 32; ++kt) {
        const int kOff = kt * 64;
#pragma unroll
        for (int it = 0; it < 4; ++it) {
            gload16(Abf + aBase + it * (32 * K_DIM) + kOff, lsA + it * 2048 + wave * 512);
            gload16(Bperm + bBase + it * (32 * K_DIM) + kOff, lsB + it * 2048 + wave * 512);
        }
        __syncthreads();
#pragma unroll
        for (int ks = 0; ks < 2; ++ks) {
            bf16x8 af[4], bfr[4];
#pragma unroll
            for (int tm = 0; tm < 4; ++tm)
                af[tm] = *(const bf16x8*)(lsA + (wm * 64 + tm * 16 + fRow) * 64 + ks * 32 + fK);
#pragma unroll
            for (int tn = 0; tn < 4; ++tn)
                bfr[tn] = *(const bf16x8*)(lsB + (wn * 64 + tn * 16 + fRow) * 64 + ks * 32 + fK);
#pragma unroll
            for (int tm = 0; tm < 4; ++tm)
#pragma unroll
                for (int tn = 0; tn < 4; ++tn)
                    acc[tm][tn] = __builtin_amdgcn_mfma_f32_16x16x32_bf16(
                        af[tm], bfr[tn], acc[tm][tn], 0, 0, 0);
        }
        __syncthreads();
    }

    // Epilogue: tn indexes gate {i,f,g,o}; j fixed per lane.
    const int j = jb * 32 + wn * 16 + fRow;
    const float b_i = bx[j] + bh[j];
    const float b_f = bx[1024 + j] + bh[1024 + j];
    const float b_g = bx[2048 + j] + bh[2048 + j];
    const float b_o = bx[3072 + j] + bh[3072 + j];
#pragma unroll
    for (int tm = 0; tm < 4; ++tm) {
#pragma unroll
        for (int r = 0; r < 4; ++r) {
            const int row = m0 + wm * 64 + tm * 16 + (lane >> 4) * 4 + r;
            float vi = acc[tm][0][r] + b_i;
            float vf = acc[tm][1][r] + b_f;
            float vg = acc[tm][2][r] + b_g;
            float vo = acc[tm][3][r] + b_o;
            float ig = 1.f / (1.f + __expf(-vi));
            float fg = 1.f / (1.f + __expf(-vf));
            float e2g = __expf(2.f * fminf(fmaxf(vg, -15.f), 15.f));
            float gg = (e2g - 1.f) / (e2g + 1.f);
            float og = 1.f / (1.f + __expf(-vo));
            float cn = fg * cin[(size_t)row * 1024 + j] + ig * gg;
            float e2c = __expf(2.f * fminf(fmaxf(cn, -15.f), 15.f));
            float hn = og * ((e2c - 1.f) / (e2c + 1.f));
            out[(size_t)row * 1024 + j] = og;
            out[(size_t)BH + (size_t)row * 1024 + j] = hn;
            out[(size_t)2 * BH + (size_t)row * 1024 + j] = cn;
        }
    }
}

extern "C" void kernel_launch(void* const* d_in, const int* in_sizes, int n_in,
                              void* d_out, int out_size, void* d_ws, size_t ws_size,
                              hipStream_t stream) {
    const float* x  = (const float*)d_in[0];
    const float* h  = (const float*)d_in[1];
    const float* c  = (const float*)d_in[2];
    const float* Wx = (const float*)d_in[3];
    const float* Wh = (const float*)d_in[4];
    const float* bx = (const float*)d_in[5];
    const float* bh = (const float*)d_in[6];
    float* out = (float*)d_out;

    unsigned short* Abf   = (unsigned short*)d_ws;                                   // 32 MB
    unsigned short* Bperm = (unsigned short*)((char*)d_ws + (size_t)B_DIM * K_DIM * 2); // 16 MB

    hipLaunchKernelGGL(build_a, dim3((B_DIM * K_DIM / 4) / 256), dim3(256), 0, stream, x, h, Abf);
    hipLaunchKernelGGL(build_b, dim3(32, 64), dim3(256), 0, stream, Wx, Wh, Bperm);
    hipLaunchKernelGGL(lstm_fused, dim3(B_DIM / 128, 32), dim3(256), 0, stream,
                       Abf, Bperm, bx, bh, c, out);
}

// Round 2
// 340.162 us; speedup vs baseline: 1.0376x; 1.0376x over previous
//
#include <hip/hip_runtime.h>
#include <hip/hip_bf16.h>

typedef __attribute__((ext_vector_type(8))) short bf16x8;
typedef __attribute__((ext_vector_type(4))) float f32x4;
typedef __attribute__((ext_vector_type(8))) unsigned short u16x8;

#define B_DIM 8192
#define H_DIM 1024
#define K_DIM 2048
#define N_DIM 4096
#define BH (B_DIM * H_DIM)

__device__ __forceinline__ unsigned short f2bf(float f) {
    union { float f; unsigned u; } v; v.f = f;
    unsigned r = v.u + 0x7FFFu + ((v.u >> 16) & 1u);   // round-to-nearest-even
    return (unsigned short)(r >> 16);
}

__device__ __forceinline__ void gload16(const void* g, void* l) {
    __builtin_amdgcn_global_load_lds(
        (const __attribute__((address_space(1))) void*)g,
        (__attribute__((address_space(3))) void*)l, 16, 0, 0);
}

// ---------------------------------------------------------------------------
// prep: blocks [0,8192): pack [x|h] fp32 -> bf16 A[8192][2048] (16B stores)
//       blocks [8192,10240): W=[Wx;Wh] -> bf16 Bperm (gate-permuted B^T)
// Row mapping for Bperm: n = gate*1024 + j; jb=j>>5, jj=j&31 ->
//   R = jb*128 + (jj>>4)*64 + gate*16 + (jj&15),  Bperm[R][k] = W[k][n]
// ---------------------------------------------------------------------------
__global__ void prep(const float* __restrict__ x, const float* __restrict__ h,
                     const float* __restrict__ Wx, const float* __restrict__ Wh,
                     unsigned short* __restrict__ Abf, unsigned short* __restrict__ Bperm) {
    __shared__ float tile[64][65];
    const int t = threadIdx.x;
    if (blockIdx.x < 8192) {
        int gid = blockIdx.x * 256 + t;             // one u16x8 (8 elems) per thread
        size_t e = (size_t)gid * 8;
        int m   = gid >> 8;                         // row (2048 elems/row)
        int col = (gid & 255) * 8;
        int p   = col >> 10;                        // 0 = x half, 1 = h half
        int k   = col & 1023;
        const float* src = (p ? h : x) + (size_t)m * 1024 + k;
        float4 v0 = *(const float4*)src;
        float4 v1 = *(const float4*)(src + 4);
        u16x8 o = { f2bf(v0.x), f2bf(v0.y), f2bf(v0.z), f2bf(v0.w),
                    f2bf(v1.x), f2bf(v1.y), f2bf(v1.z), f2bf(v1.w) };
        *(u16x8*)(Abf + e) = o;
        return;
    }
    const int bz = blockIdx.x - 8192;
    const int k0 = (bz & 31) * 64;                  // 32 tiles over K
    const int n0 = (bz >> 5) * 64;                  // 64 tiles over N
#pragma unroll
    for (int it = 0; it < 4; ++it) {
        int lin = it * 256 + t;                     // 0..1023 float4 slots
        int kl  = lin >> 4;
        int n4  = lin & 15;
        int k   = k0 + kl;
        const float* src = (k < 1024) ? (Wx + (size_t)k * 4096 + n0 + n4 * 4)
                                      : (Wh + (size_t)(k - 1024) * 4096 + n0 + n4 * 4);
        float4 v = *(const float4*)src;
        tile[kl][n4 * 4 + 0] = v.x;
        tile[kl][n4 * 4 + 1] = v.y;
        tile[kl][n4 * 4 + 2] = v.z;
        tile[kl][n4 * 4 + 3] = v.w;
    }
    __syncthreads();
#pragma unroll
    for (int it = 0; it < 2; ++it) {
        int lin = it * 256 + t;                     // 0..511
        int nl  = lin >> 3;
        int ch  = lin & 7;
        int n    = n0 + nl;
        int gate = n >> 10;
        int j    = n & 1023;
        int jb   = j >> 5;
        int jj   = j & 31;
        int R    = jb * 128 + (jj >> 4) * 64 + gate * 16 + (jj & 15);
        u16x8 o;
#pragma unroll
        for (int q = 0; q < 8; ++q) o[q] = f2bf(tile[ch * 8 + q][nl]);
        *(u16x8*)(Bperm + (size_t)R * 2048 + k0 + ch * 8) = o;
    }
}

// ---------------------------------------------------------------------------
// fused GEMM + LSTM epilogue. 128x128 tile, BK=64, 4 waves, 16x16x32 bf16.
// XOR-swizzled LDS: physical chunk p holds logical (row=p>>3, c=(p&7)^(row&7))
// -> staging source column = ((tid&7) ^ ((tid>>3)&7)) * 8 (dest fixed lane*16),
//    fragment read offset = row*64 + 8*((ks*4 + (lane>>4)) ^ (row&7)).
// ---------------------------------------------------------------------------
__global__ __launch_bounds__(256, 4) void lstm_fused(
    const unsigned short* __restrict__ Abf,   // [8192][2048] bf16
    const unsigned short* __restrict__ Bperm, // [4096][2048] bf16 (permuted B^T)
    const float* __restrict__ bx, const float* __restrict__ bh,
    const float* __restrict__ cin, float* __restrict__ out) {
    __shared__ unsigned short lsA[128 * 64];
    __shared__ unsigned short lsB[128 * 64];

    const int tid  = threadIdx.x;
    const int wave = tid >> 6;
    const int lane = tid & 63;
    const int m0 = blockIdx.x * 128;
    const int jb = blockIdx.y;                  // 0..31
    const int wm = wave >> 1;
    const int wn = wave & 1;

    f32x4 acc[4][4];
#pragma unroll
    for (int i = 0; i < 4; ++i)
#pragma unroll
        for (int j = 0; j < 4; ++j) acc[i][j] = (f32x4){0.f, 0.f, 0.f, 0.f};

    const int sRow   = tid >> 3;                              // 0..31 (+ it*32)
    const int sChunk = (((tid & 7) ^ ((tid >> 3) & 7))) * 8;  // swizzled source col
    const int aBase = (m0 + sRow) * K_DIM + sChunk;
    const int bBase = (jb * 128 + sRow) * K_DIM + sChunk;

    const int fRow  = lane & 15;
    const int qBase = lane >> 4;                // 0..3
    const int rx    = fRow & 7;                 // row XOR key

    for (int kt = 0; kt < 32; ++kt) {
        const int kOff = kt * 64;
#pragma unroll
        for (int it = 0; it < 4; ++it) {
            gload16(Abf + aBase + it * (32 * K_DIM) + kOff, lsA + it * 2048 + wave * 512);
            gload16(Bperm + bBase + it * (32 * K_DIM) + kOff, lsB + it * 2048 + wave * 512);
        }
        __syncthreads();
#pragma unroll
        for (int ks = 0; ks < 2; ++ks) {
            bf16x8 af[4], bfr[4];
            const int qPhys = (ks * 4 + qBase) ^ rx;          // physical chunk
#pragma unroll
            for (int tm = 0; tm < 4; ++tm)
                af[tm] = *(const bf16x8*)(lsA + (wm * 64 + tm * 16 + fRow) * 64 + qPhys * 8);
#pragma unroll
            for (int tn = 0; tn < 4; ++tn)
                bfr[tn] = *(const bf16x8*)(lsB + (wn * 64 + tn * 16 + fRow) * 64 + qPhys * 8);
#pragma unroll
            for (int tm = 0; tm < 4; ++tm)
#pragma unroll
                for (int tn = 0; tn < 4; ++tn)
                    acc[tm][tn] = __builtin_amdgcn_mfma_f32_16x16x32_bf16(
                        af[tm], bfr[tn], acc[tm][tn], 0, 0, 0);
        }
        __syncthreads();
    }

    // Epilogue: tn indexes gate {i,f,g,o}; j fixed per lane.
    const int j = jb * 32 + wn * 16 + fRow;
    const float b_i = bx[j] + bh[j];
    const float b_f = bx[1024 + j] + bh[1024 + j];
    const float b_g = bx[2048 + j] + bh[2048 + j];
    const float b_o = bx[3072 + j] + bh[3072 + j];
#pragma unroll
    for (int tm = 0; tm < 4; ++tm) {
#pragma unroll
        for (int r = 0; r < 4; ++r) {
            const int row = m0 + wm * 64 + tm * 16 + (lane >> 4) * 4 + r;
            float vi = acc[tm][0][r] + b_i;
            float vf = acc[tm][1][r] + b_f;
            float vg = acc[tm][2][r] + b_g;
            float vo = acc[tm][3][r] + b_o;
            float ig = 1.f / (1.f + __expf(-vi));
            float fg = 1.f / (1.f + __expf(-vf));
            float e2g = __expf(2.f * fminf(fmaxf(vg, -15.f), 15.f));
            float gg = (e2g - 1.f) / (e2g + 1.f);
            float og = 1.f / (1.f + __expf(-vo));
            float cn = fg * cin[(size_t)row * 1024 + j] + ig * gg;
            float e2c = __expf(2.f * fminf(fmaxf(cn, -15.f), 15.f));
            float hn = og * ((e2c - 1.f) / (e2c + 1.f));
            out[(size_t)row * 1024 + j] = og;
            out[(size_t)BH + (size_t)row * 1024 + j] = hn;
            out[(size_t)2 * BH + (size_t)row * 1024 + j] = cn;
        }
    }
}

extern "C" void kernel_launch(void* const* d_in, const int* in_sizes, int n_in,
                              void* d_out, int out_size, void* d_ws, size_t ws_size,
                              hipStream_t stream) {
    const float* x  = (const float*)d_in[0];
    const float* h  = (const float*)d_in[1];
    const float* c  = (const float*)d_in[2];
    const float* Wx = (const float*)d_in[3];
    const float* Wh = (const float*)d_in[4];
    const float* bx = (const float*)d_in[5];
    const float* bh = (const float*)d_in[6];
    float* out = (float*)d_out;

    unsigned short* Abf   = (unsigned short*)d_ws;                                      // 32 MB
    unsigned short* Bperm = (unsigned short*)((char*)d_ws + (size_t)B_DIM * K_DIM * 2); // 16 MB

    hipLaunchKernelGGL(prep, dim3(8192 + 2048), dim3(256), 0, stream, x, h, Wx, Wh, Abf, Bperm);
    hipLaunchKernelGGL(lstm_fused, dim3(B_DIM / 128, 32), dim3(256), 0, stream,
                       Abf, Bperm, bx, bh, c, out);
}